// Round 2
// baseline (412.392 us; speedup 1.0000x reference)
//
#include <hip/hip_runtime.h>
#include <stdint.h>

// ---------------------------------------------------------------------------
// SelfAttn: B=4, W=H=64, C=256, C2=128, N=W*H=4096.
// pq = raw q buffer viewed [128,4096]  (Q_rows[n,c] = q_flat[c*4096+n];
//      inverse: flat = pp*128+d -> c = pp>>5, n = (pp&31)*128+d)
// pv = raw v buffer viewed [256,4096]  (natural layout == PV B-operand layout)
// energy = Qrm @ Krm^T (K=128), softmax over keys, O[n,c] = sum_m P[n,m] V[m,c]
// final[b, c*4096+n] = gamma*O[n,c]/l[n] + x[b, c*4096+n]
// ---------------------------------------------------------------------------

typedef __attribute__((ext_vector_type(8))) short  short8;   // 8 x bf16 (4 VGPRs)
typedef __attribute__((ext_vector_type(4))) float  f32x4;
typedef __attribute__((ext_vector_type(4))) float  f32x4v;
typedef __attribute__((ext_vector_type(4))) unsigned short u16x4;

#define MFMA_BF16 __builtin_amdgcn_mfma_f32_16x16x32_bf16

__device__ __forceinline__ unsigned short f2bf(float f) {
    union { float f; uint32_t u; } v; v.f = f;
    uint32_t r = (v.u + 0x7FFFu + ((v.u >> 16) & 1u)) >> 16;   // RNE
    return (unsigned short)r;
}
__device__ __forceinline__ float bf2f(unsigned short h) {
    union { uint32_t u; float f; } v; v.u = ((uint32_t)h) << 16;
    return v.f;
}

// --- K1: Wt[512][256] bf16 (transposed, fused qkv) + bias[512] f32 ---------
__global__ void prep_w(const float* __restrict__ Wq, const float* __restrict__ bq,
                       const float* __restrict__ Wk, const float* __restrict__ bk,
                       const float* __restrict__ Wv, const float* __restrict__ bv,
                       unsigned short* __restrict__ Wt, float* __restrict__ bias) {
    int g = blockIdx.x * 256 + threadIdx.x;           // 512*256 = 131072 threads
    int c = g & 255, d = g >> 8;
    float val;
    if (d < 128)      val = Wq[c * 128 + d];
    else if (d < 256) val = Wk[c * 128 + (d - 128)];
    else              val = Wv[c * 256 + (d - 256)];
    Wt[d * 256 + c] = f2bf(val);
    if (g < 512) {
        float bb;
        if (g < 128)      bb = bq[g];
        else if (g < 256) bb = bk[g - 128];
        else              bb = bv[g - 256];
        bias[g] = bb;
    }
}

// --- K2: fused QKV projection. 512 blocks:
//   [0,128)   Q-kind: block(b,a) pixels {a+32*cc}, d 0..127   -> Qrm contiguous tile
//   [128,256) K-kind: same pixels, d 128..255                 -> Krm contiguous tile
//   [256,512) V-kind: block(b,pg,half) consecutive pixels, dv half*128..+127 -> Vbf
// Reads x f32 directly (conv fused). Q/K epilogue transposes through LDS so the
// global write is one contiguous 32KB coalesced tile.
__global__ __launch_bounds__(256) void proj(
        const float* __restrict__ x, const unsigned short* __restrict__ Wt,
        const float* __restrict__ bias,
        unsigned short* __restrict__ Qrm, unsigned short* __restrict__ Krm,
        unsigned short* __restrict__ Vbf) {
    __shared__ unsigned short T[128 * 136];           // transpose tile (Q/K kinds)
    int bid = blockIdx.x;
    int tid = threadIdx.x;
    int wave = tid >> 6, lane = tid & 63;
    int l16 = lane & 15, quad = lane >> 4;

    int kind, b, a, vh = 0;
    if (bid < 256) { kind = bid >> 7; int s = bid & 127; b = s >> 5; a = s & 31; }
    else           { kind = 2; int s = bid - 256; vh = s >> 7; b = (s >> 5) & 3; a = s & 31; }

    // A-frags: 2 groups of 16 pixel-rows per wave, full K=256, f32->bf16 inline
    short8 af[2][8];
    #pragma unroll
    for (int g = 0; g < 2; ++g) {
        int p_local = wave * 32 + g * 16 + l16;
        int pix = (kind == 2) ? (b * 4096 + a * 128 + p_local)
                              : (b * 4096 + a + 32 * p_local);
        const float* xr = x + (size_t)pix * 256;
        #pragma unroll
        for (int kk = 0; kk < 8; ++kk) {
            f32x4v u0 = *(const f32x4v*)(xr + kk * 32 + quad * 8);
            f32x4v u1 = *(const f32x4v*)(xr + kk * 32 + quad * 8 + 4);
            short8 h;
            h[0] = (short)f2bf(u0[0]); h[1] = (short)f2bf(u0[1]);
            h[2] = (short)f2bf(u0[2]); h[3] = (short)f2bf(u0[3]);
            h[4] = (short)f2bf(u1[0]); h[5] = (short)f2bf(u1[1]);
            h[6] = (short)f2bf(u1[2]); h[7] = (short)f2bf(u1[3]);
            af[g][kk] = h;
        }
    }

    if (kind < 2) {
        int dbase = kind * 128;
        unsigned short* out = kind ? Krm : Qrm;
        #pragma unroll 1
        for (int dt = 0; dt < 8; ++dt) {
            int d = dbase + dt * 16 + l16;
            float bval = bias[d];
            f32x4 acc0 = {0.f,0.f,0.f,0.f}, acc1 = {0.f,0.f,0.f,0.f};
            #pragma unroll
            for (int kk = 0; kk < 8; ++kk) {
                short8 wrow = *(const short8*)(Wt + d * 256 + kk * 32 + quad * 8);
                acc0 = MFMA_BF16(af[0][kk], wrow, acc0, 0, 0, 0);
                acc1 = MFMA_BF16(af[1][kk], wrow, acc1, 0, 0, 0);
            }
            #pragma unroll
            for (int g = 0; g < 2; ++g) {
                f32x4 acc = g ? acc1 : acc0;
                u16x4 pk;
                #pragma unroll
                for (int reg = 0; reg < 4; ++reg) pk[reg] = f2bf(acc[reg] + bval);
                // D: row(pixel)=quad*4+reg, col(d)=l16. Store transposed [d][c].
                *(u16x4*)(T + (dt * 16 + l16) * 136 + wave * 32 + g * 16 + quad * 4) = pk;
            }
        }
        __syncthreads();
        // tile rows d_local 0..127 -> out[(b<<19) + (a*128 + d_local)*128 + c]
        unsigned short* ob = out + (b << 19) + a * 128 * 128;
        #pragma unroll
        for (int it = 0; it < 8; ++it) {
            int ci = it * 256 + tid;                   // 2048 chunks of 8 u16
            int row = ci >> 4, cj = ci & 15;
            *(short8*)(ob + row * 128 + cj * 8) = *(const short8*)(T + row * 136 + cj * 8);
        }
    } else {
        #pragma unroll 1
        for (int dt = 0; dt < 8; ++dt) {
            int dv = vh * 128 + dt * 16 + l16;         // 0..255
            int d = 256 + dv;
            float bval = bias[d];
            f32x4 acc0 = {0.f,0.f,0.f,0.f}, acc1 = {0.f,0.f,0.f,0.f};
            #pragma unroll
            for (int kk = 0; kk < 8; ++kk) {
                short8 wrow = *(const short8*)(Wt + d * 256 + kk * 32 + quad * 8);
                acc0 = MFMA_BF16(af[0][kk], wrow, acc0, 0, 0, 0);
                acc1 = MFMA_BF16(af[1][kk], wrow, acc1, 0, 0, 0);
            }
            #pragma unroll
            for (int g = 0; g < 2; ++g) {
                f32x4 acc = g ? acc1 : acc0;
                #pragma unroll
                for (int reg = 0; reg < 4; ++reg) {
                    int p_local = wave * 32 + g * 16 + quad * 4 + reg;
                    Vbf[(b << 20) + (a * 128 + p_local) * 256 + dv] = f2bf(acc[reg] + bval);
                }
            }
        }
    }
}

// --- K3: flash attention, 4-way key split, S^T formulation -----------------
// grid 512 = 4 batch * 32 qtiles * 4 ksplits; 4 waves * 32 queries each.
// S^T = MFMA(A=K, B=Q): query on lane&15 -> softmax = in-lane + 2 shfls;
// P written as packed b64, read back as b128 A-frags. K loaded from global
// (L1-hot, 4-wave reuse), prefetched one tile ahead. 2 barriers per tile.
__global__ __launch_bounds__(256, 2) void attn(
        const unsigned short* __restrict__ Qrm, const unsigned short* __restrict__ Krm,
        const unsigned short* __restrict__ Vbf, unsigned short* __restrict__ Opart,
        float* __restrict__ Mpart, float* __restrict__ Lpart) {

    __shared__ unsigned short Vs[256 * 72];            // V tile [c=256][m=64 +pad]
    __shared__ unsigned short Ps[4 * 32 * 72];         // per-wave P [n=32][m=64 +pad]

    int bid = blockIdx.x;
    int ks = bid & 3, qt = (bid >> 2) & 31, b = bid >> 7;
    int tid = threadIdx.x;
    int wave = tid >> 6, lane = tid & 63;
    int l16 = lane & 15, quad = lane >> 4;

    const unsigned short* Qb = Qrm + (b << 19);
    const unsigned short* Kb = Krm + (b << 19);
    const unsigned short* Vb = Vbf + (b << 20);
    unsigned short* Pw = Ps + wave * (32 * 72);

    int n0 = qt * 128 + wave * 32;

    // Q B-frags: resident for whole kernel
    short8 qf[2][4];
    #pragma unroll
    for (int r = 0; r < 2; ++r)
        #pragma unroll
        for (int kk = 0; kk < 4; ++kk)
            qf[r][kk] = *(const short8*)(Qb + (n0 + r * 16 + l16) * 128 + kk * 32 + quad * 8);

    f32x4 O[2][16];
    #pragma unroll
    for (int r = 0; r < 2; ++r)
        #pragma unroll
        for (int t = 0; t < 16; ++t) O[r][t] = (f32x4){0.f,0.f,0.f,0.f};
    float m_run[2] = {-1e30f, -1e30f}, l_run[2] = {0.f, 0.f};   // per (r, l16-query)

    const int m_base = ks * 1024;

    // K A-frags for tile 0 (prefetched)
    short8 kf[4][4];
    #pragma unroll
    for (int ksub = 0; ksub < 4; ++ksub)
        #pragma unroll
        for (int kk = 0; kk < 4; ++kk)
            kf[ksub][kk] = *(const short8*)(Kb + (m_base + ksub * 16 + l16) * 128 + kk * 32 + quad * 8);

    #pragma unroll 1
    for (int kt = 0; kt < 16; ++kt) {
        int m0 = m_base + kt * 64;
        __syncthreads();                               // protect prev tile Vs
        #pragma unroll
        for (int i = 0; i < 8; ++i) {                  // stage V-tile [256][64]
            int idx = i * 256 + tid, row = idx >> 3, ch = idx & 7;
            *(short8*)(Vs + row * 72 + ch * 8) =
                *(const short8*)(Vb + row * 4096 + m0 + ch * 8);
        }
        __syncthreads();

        // S^T[m][n]: row = m-within-16 (quad*4+reg), col = n (l16)
        f32x4 S[2][4];
        #pragma unroll
        for (int r = 0; r < 2; ++r)
            #pragma unroll
            for (int j = 0; j < 4; ++j) S[r][j] = (f32x4){0.f,0.f,0.f,0.f};
        #pragma unroll
        for (int ksub = 0; ksub < 4; ++ksub) {
            #pragma unroll
            for (int kk = 0; kk < 4; ++kk) {
                S[0][ksub] = MFMA_BF16(kf[ksub][kk], qf[0][kk], S[0][ksub], 0, 0, 0);
                S[1][ksub] = MFMA_BF16(kf[ksub][kk], qf[1][kk], S[1][ksub], 0, 0, 0);
            }
        }
        // prefetch next K-tile (in flight during softmax+PV)
        if (kt < 15) {
            int m1 = m0 + 64;
            #pragma unroll
            for (int ksub = 0; ksub < 4; ++ksub)
                #pragma unroll
                for (int kk = 0; kk < 4; ++kk)
                    kf[ksub][kk] = *(const short8*)(Kb + (m1 + ksub * 16 + l16) * 128 + kk * 32 + quad * 8);
        }

        // online softmax per query n = n0 + r*16 + l16 (replicated over quads)
        #pragma unroll
        for (int r = 0; r < 2; ++r) {
            float mx = -1e30f;
            #pragma unroll
            for (int ksub = 0; ksub < 4; ++ksub)
                #pragma unroll
                for (int reg = 0; reg < 4; ++reg) mx = fmaxf(mx, S[r][ksub][reg]);
            mx = fmaxf(mx, __shfl_xor(mx, 16));
            mx = fmaxf(mx, __shfl_xor(mx, 32));
            float mnew  = fmaxf(m_run[r], mx);
            float alpha = __expf(m_run[r] - mnew);
            float rs = 0.f;
            #pragma unroll
            for (int ksub = 0; ksub < 4; ++ksub) {
                u16x4 pk;
                #pragma unroll
                for (int reg = 0; reg < 4; ++reg) {
                    float p = __expf(S[r][ksub][reg] - mnew);
                    rs += p;
                    pk[reg] = f2bf(p);
                }
                // P[n][m]: n = r*16+l16, m = ksub*16 + quad*4 + reg  -> b64
                *(u16x4*)(Pw + (r * 16 + l16) * 72 + ksub * 16 + quad * 4) = pk;
            }
            rs += __shfl_xor(rs, 16);
            rs += __shfl_xor(rs, 32);
            l_run[r] = l_run[r] * alpha + rs;
            m_run[r] = mnew;
            // transpose alpha to O-row indexing (O rows n' = quad*4+reg)
            float a0 = __shfl(alpha, quad * 4 + 0);
            float a1 = __shfl(alpha, quad * 4 + 1);
            float a2 = __shfl(alpha, quad * 4 + 2);
            float a3 = __shfl(alpha, quad * 4 + 3);
            #pragma unroll
            for (int t = 0; t < 16; ++t) {
                O[r][t][0] *= a0; O[r][t][1] *= a1;
                O[r][t][2] *= a2; O[r][t][3] *= a3;
            }
        }

        // PV: O[n,c] += P[n,m] V[m,c]  (Ps per-wave private: no barrier needed)
        #pragma unroll
        for (int s = 0; s < 2; ++s) {
            short8 a0 = *(const short8*)(Pw + (l16) * 72 + s * 32 + quad * 8);
            short8 a1 = *(const short8*)(Pw + (16 + l16) * 72 + s * 32 + quad * 8);
            #pragma unroll
            for (int t = 0; t < 16; ++t) {
                short8 bv = *(const short8*)(Vs + (t * 16 + l16) * 72 + s * 32 + quad * 8);
                O[0][t] = MFMA_BF16(a0, bv, O[0][t], 0, 0, 0);
                O[1][t] = MFMA_BF16(a1, bv, O[1][t], 0, 0, 0);
            }
        }
    }

    // epilogue: unnormalized O (bf16) + per-query m,l
    unsigned short* Op = Opart + ((size_t)(ks * 4 + b) << 20);
    #pragma unroll
    for (int r = 0; r < 2; ++r)
        #pragma unroll
        for (int t = 0; t < 16; ++t)
            #pragma unroll
            for (int reg = 0; reg < 4; ++reg) {
                int n = n0 + r * 16 + quad * 4 + reg;
                int c = t * 16 + l16;
                Op[n * 256 + c] = f2bf(O[r][t][reg]);
            }
    if (lane < 16) {
        #pragma unroll
        for (int r = 0; r < 2; ++r) {
            int n = n0 + r * 16 + lane;
            Mpart[(ks * 4 + b) * 4096 + n] = m_run[r];
            Lpart[(ks * 4 + b) * 4096 + n] = l_run[r];
        }
    }
}

// --- K4: merge 4 key-splits, normalize, gamma*O+x, transpose [n,c]->[c,n] --
__global__ __launch_bounds__(256) void merge_out(
        const unsigned short* __restrict__ Opart, const float* __restrict__ Mpart,
        const float* __restrict__ Lpart, const float* __restrict__ x,
        const float* __restrict__ gamma, float* __restrict__ out) {
    __shared__ float tile[64][65];
    __shared__ float wsm[4][64];                       // merge weights per n
    int b  = blockIdx.x >> 6;
    int n0 = (blockIdx.x & 63) << 6;
    int tid = threadIdx.x;
    float g = gamma[0];
    if (tid < 64) {
        int n = n0 + tid;
        float ms[4], M = -1e30f;
        #pragma unroll
        for (int s = 0; s < 4; ++s) {
            ms[s] = Mpart[(s * 4 + b) * 4096 + n];
            M = fmaxf(M, ms[s]);
        }
        float e[4], L = 0.f;
        #pragma unroll
        for (int s = 0; s < 4; ++s) {
            e[s] = __expf(ms[s] - M);
            L += e[s] * Lpart[(s * 4 + b) * 4096 + n];
        }
        float inv = g / L;
        #pragma unroll
        for (int s = 0; s < 4; ++s) wsm[s][tid] = e[s] * inv;
    }
    __syncthreads();
    int cl  = tid & 63, nl4 = tid >> 6;                // phase 1
    int nl  = tid & 63, cl4 = tid >> 6;                // phase 2
    for (int cc = 0; cc < 4; ++cc) {
        for (int i = 0; i < 16; ++i) {                 // phase 1: coalesced Opart reads
            int n = n0 + i * 4 + nl4;
            int c = (cc << 6) + cl;
            float On = 0.f;
            #pragma unroll
            for (int s = 0; s < 4; ++s)
                On += wsm[s][i * 4 + nl4] * bf2f(Opart[((size_t)(s * 4 + b) << 20) + n * 256 + c]);
            tile[cl][i * 4 + nl4] = On;
        }
        __syncthreads();
        for (int j = 0; j < 16; ++j) {                 // phase 2: coalesced out writes
            int c = (cc << 6) + j * 4 + cl4;
            int idx = (b << 20) + c * 4096 + n0 + nl;
            out[idx] = tile[j * 4 + cl4][nl] + x[idx];
        }
        __syncthreads();
    }
}

// ---------------------------------------------------------------------------
extern "C" void kernel_launch(void* const* d_in, const int* in_sizes, int n_in,
                              void* d_out, int out_size, void* d_ws, size_t ws_size,
                              hipStream_t stream) {
    const float* x     = (const float*)d_in[0];
    const float* Wq    = (const float*)d_in[1];
    const float* bq    = (const float*)d_in[2];
    const float* Wk    = (const float*)d_in[3];
    const float* bk    = (const float*)d_in[4];
    const float* Wv    = (const float*)d_in[5];
    const float* bv    = (const float*)d_in[6];
    const float* gamma = (const float*)d_in[7];
    float* out = (float*)d_out;

    if (ws_size < 51120128u) return;   // need ~49 MB scratch

    char* ws = (char*)d_ws;
    unsigned short* Wt    = (unsigned short*)(ws);             //    262,144 B
    float*          bias  = (float*)        (ws +   262144);   //      2,048 B
    unsigned short* Qrm   = (unsigned short*)(ws +   264192);  //  4,194,304 B
    unsigned short* Krm   = (unsigned short*)(ws +  4458496);  //  4,194,304 B
    unsigned short* Vbf   = (unsigned short*)(ws +  8652800);  //  8,388,608 B
    unsigned short* Opart = (unsigned short*)(ws + 17041408);  // 33,554,432 B
    float*          Mpart = (float*)        (ws + 50595840);   //    262,144 B
    float*          Lpart = (float*)        (ws + 50857984);   //    262,144 B

    prep_w   <<<512, 256, 0, stream>>>(Wq, bq, Wk, bk, Wv, bv, Wt, bias);
    proj     <<<512, 256, 0, stream>>>(x, Wt, bias, Qrm, Krm, Vbf);
    attn     <<<512, 256, 0, stream>>>(Qrm, Krm, Vbf, Opart, Mpart, Lpart);
    merge_out<<<256, 256, 0, stream>>>(Opart, Mpart, Lpart, x, gamma, out);
}

// Round 3
// 247.845 us; speedup vs baseline: 1.6639x; 1.6639x over previous
//
#include <hip/hip_runtime.h>
#include <stdint.h>

// ---------------------------------------------------------------------------
// SelfAttn: B=4, W=H=64, C=256, C2=128, N=W*H=4096.
// pq = raw q buffer viewed [128,4096]  (Q_rows[n,c] = q_flat[c*4096+n];
//      inverse: flat = pp*128+d -> c = pp>>5, n = (pp&31)*128+d)
// pv = raw v buffer viewed [256,4096]  (natural layout == PV B-operand layout)
// energy = Qrm @ Krm^T (K=128), softmax over keys, O[n,c] = sum_m P[n,m] V[m,c]
// final[b, c*4096+n] = gamma*O[n,c]/l[n] + x[b, c*4096+n]
//
// R2 post-mortem: K-in-registers (kf[4][4]=64 VGPRs live across loop) spilled
// (FETCH 383MB/WRITE 574MB scratch traffic). K stays in LDS; registers hold
// only Q (32) + O (128 AGPR) + S (32).
// ---------------------------------------------------------------------------

typedef __attribute__((ext_vector_type(8))) short  short8;   // 8 x bf16 (4 VGPRs)
typedef __attribute__((ext_vector_type(4))) float  f32x4;
typedef __attribute__((ext_vector_type(4))) float  f32x4v;
typedef __attribute__((ext_vector_type(4))) unsigned short u16x4;

#define MFMA_BF16 __builtin_amdgcn_mfma_f32_16x16x32_bf16

__device__ __forceinline__ unsigned short f2bf(float f) {
    union { float f; uint32_t u; } v; v.f = f;
    uint32_t r = (v.u + 0x7FFFu + ((v.u >> 16) & 1u)) >> 16;   // RNE
    return (unsigned short)r;
}
__device__ __forceinline__ float bf2f(unsigned short h) {
    union { uint32_t u; float f; } v; v.u = ((uint32_t)h) << 16;
    return v.f;
}

// --- K1: Wt[512][256] bf16 (transposed, fused qkv) + bias[512] f32 ---------
__global__ void prep_w(const float* __restrict__ Wq, const float* __restrict__ bq,
                       const float* __restrict__ Wk, const float* __restrict__ bk,
                       const float* __restrict__ Wv, const float* __restrict__ bv,
                       unsigned short* __restrict__ Wt, float* __restrict__ bias) {
    int g = blockIdx.x * 256 + threadIdx.x;           // 512*256 = 131072 threads
    int c = g & 255, d = g >> 8;
    float val;
    if (d < 128)      val = Wq[c * 128 + d];
    else if (d < 256) val = Wk[c * 128 + (d - 128)];
    else              val = Wv[c * 256 + (d - 256)];
    Wt[d * 256 + c] = f2bf(val);
    if (g < 512) {
        float bb;
        if (g < 128)      bb = bq[g];
        else if (g < 256) bb = bk[g - 128];
        else              bb = bv[g - 256];
        bias[g] = bb;
    }
}

// --- K2: fused QKV projection. 512 blocks:
//   [0,128)   Q-kind: block(b,a) pixels {a+32*cc}, d 0..127   -> Qrm contiguous tile
//   [128,256) K-kind: same pixels, d 128..255                 -> Krm contiguous tile
//   [256,512) V-kind: block(b,pg,half) consecutive pixels, dv half*128..+127 -> Vbf
// Reads x f32 directly (conv fused). Q/K epilogue transposes through LDS so the
// global write is one contiguous 32KB coalesced tile.
__global__ __launch_bounds__(256) void proj(
        const float* __restrict__ x, const unsigned short* __restrict__ Wt,
        const float* __restrict__ bias,
        unsigned short* __restrict__ Qrm, unsigned short* __restrict__ Krm,
        unsigned short* __restrict__ Vbf) {
    __shared__ unsigned short T[128 * 136];           // transpose tile (Q/K kinds)
    int bid = blockIdx.x;
    int tid = threadIdx.x;
    int wave = tid >> 6, lane = tid & 63;
    int l16 = lane & 15, quad = lane >> 4;

    int kind, b, a, vh = 0;
    if (bid < 256) { kind = bid >> 7; int s = bid & 127; b = s >> 5; a = s & 31; }
    else           { kind = 2; int s = bid - 256; vh = s >> 7; b = (s >> 5) & 3; a = s & 31; }

    // A-frags: 2 groups of 16 pixel-rows per wave, full K=256, f32->bf16 inline
    short8 af[2][8];
    #pragma unroll
    for (int g = 0; g < 2; ++g) {
        int p_local = wave * 32 + g * 16 + l16;
        int pix = (kind == 2) ? (b * 4096 + a * 128 + p_local)
                              : (b * 4096 + a + 32 * p_local);
        const float* xr = x + (size_t)pix * 256;
        #pragma unroll
        for (int kk = 0; kk < 8; ++kk) {
            f32x4v u0 = *(const f32x4v*)(xr + kk * 32 + quad * 8);
            f32x4v u1 = *(const f32x4v*)(xr + kk * 32 + quad * 8 + 4);
            short8 h;
            h[0] = (short)f2bf(u0[0]); h[1] = (short)f2bf(u0[1]);
            h[2] = (short)f2bf(u0[2]); h[3] = (short)f2bf(u0[3]);
            h[4] = (short)f2bf(u1[0]); h[5] = (short)f2bf(u1[1]);
            h[6] = (short)f2bf(u1[2]); h[7] = (short)f2bf(u1[3]);
            af[g][kk] = h;
        }
    }

    if (kind < 2) {
        int dbase = kind * 128;
        unsigned short* out = kind ? Krm : Qrm;
        #pragma unroll 1
        for (int dt = 0; dt < 8; ++dt) {
            int d = dbase + dt * 16 + l16;
            float bval = bias[d];
            f32x4 acc0 = {0.f,0.f,0.f,0.f}, acc1 = {0.f,0.f,0.f,0.f};
            #pragma unroll
            for (int kk = 0; kk < 8; ++kk) {
                short8 wrow = *(const short8*)(Wt + d * 256 + kk * 32 + quad * 8);
                acc0 = MFMA_BF16(af[0][kk], wrow, acc0, 0, 0, 0);
                acc1 = MFMA_BF16(af[1][kk], wrow, acc1, 0, 0, 0);
            }
            #pragma unroll
            for (int g = 0; g < 2; ++g) {
                f32x4 acc = g ? acc1 : acc0;
                u16x4 pk;
                #pragma unroll
                for (int reg = 0; reg < 4; ++reg) pk[reg] = f2bf(acc[reg] + bval);
                // D: row(pixel)=quad*4+reg, col(d)=l16. Store transposed [d][c].
                *(u16x4*)(T + (dt * 16 + l16) * 136 + wave * 32 + g * 16 + quad * 4) = pk;
            }
        }
        __syncthreads();
        // tile rows d_local 0..127 -> out[(b<<19) + (a*128 + d_local)*128 + c]
        unsigned short* ob = out + (b << 19) + a * 128 * 128;
        #pragma unroll
        for (int it = 0; it < 8; ++it) {
            int ci = it * 256 + tid;                   // 2048 chunks of 8 u16
            int row = ci >> 4, cj = ci & 15;
            *(short8*)(ob + row * 128 + cj * 8) = *(const short8*)(T + row * 136 + cj * 8);
        }
    } else {
        #pragma unroll 1
        for (int dt = 0; dt < 8; ++dt) {
            int dv = vh * 128 + dt * 16 + l16;         // 0..255
            int d = 256 + dv;
            float bval = bias[d];
            f32x4 acc0 = {0.f,0.f,0.f,0.f}, acc1 = {0.f,0.f,0.f,0.f};
            #pragma unroll
            for (int kk = 0; kk < 8; ++kk) {
                short8 wrow = *(const short8*)(Wt + d * 256 + kk * 32 + quad * 8);
                acc0 = MFMA_BF16(af[0][kk], wrow, acc0, 0, 0, 0);
                acc1 = MFMA_BF16(af[1][kk], wrow, acc1, 0, 0, 0);
            }
            #pragma unroll
            for (int g = 0; g < 2; ++g) {
                f32x4 acc = g ? acc1 : acc0;
                #pragma unroll
                for (int reg = 0; reg < 4; ++reg) {
                    int p_local = wave * 32 + g * 16 + quad * 4 + reg;
                    Vbf[(b << 20) + (a * 128 + p_local) * 256 + dv] = f2bf(acc[reg] + bval);
                }
            }
        }
    }
}

// --- K3: flash attention, 4-way key split, S^T formulation, K in LDS -------
// grid 512 = 4 batch * 32 qtiles * 4 ksplits; 4 waves * 32 queries each.
// S^T = MFMA(A=K from LDS, B=Q regs): query on lane&15 -> softmax = in-lane
// + 2 shfls; P written packed b64 into the K region (overlay, barrier-guarded),
// read back as b128 A-frags for PV. Registers: qf 32 + O 128(AGPR) + S 32.
__global__ __launch_bounds__(256, 2) void attn(
        const unsigned short* __restrict__ Qrm, const unsigned short* __restrict__ Krm,
        const unsigned short* __restrict__ Vbf, unsigned short* __restrict__ Opart,
        float* __restrict__ Mpart, float* __restrict__ Lpart) {

    // KP: K tile [64][136] (8704 u16) overlaid with P [4 waves][32][72] (9216 u16)
    __shared__ unsigned short KP[9216];
    __shared__ unsigned short Vs[256 * 72];            // V tile [c=256][m=64 +pad]

    int bid = blockIdx.x;
    int ks = bid & 3, qt = (bid >> 2) & 31, b = bid >> 7;
    int tid = threadIdx.x;
    int wave = tid >> 6, lane = tid & 63;
    int l16 = lane & 15, quad = lane >> 4;

    const unsigned short* Qb = Qrm + (b << 19);
    const unsigned short* Kb = Krm + (b << 19);
    const unsigned short* Vb = Vbf + (b << 20);
    unsigned short* Pw = KP + wave * (32 * 72);

    int n0 = qt * 128 + wave * 32;

    // Q B-frags: resident for whole kernel (B[k][n]: n=lane&15, k=quad*8+j)
    short8 qf[2][4];
    #pragma unroll
    for (int r = 0; r < 2; ++r)
        #pragma unroll
        for (int kk = 0; kk < 4; ++kk)
            qf[r][kk] = *(const short8*)(Qb + (n0 + r * 16 + l16) * 128 + kk * 32 + quad * 8);

    f32x4 O[2][16];
    #pragma unroll
    for (int r = 0; r < 2; ++r)
        #pragma unroll
        for (int t = 0; t < 16; ++t) O[r][t] = (f32x4){0.f,0.f,0.f,0.f};
    float m_run[2] = {-1e30f, -1e30f}, l_run[2] = {0.f, 0.f};   // per (r, l16-query)

    const int m_base = ks * 1024;

    #pragma unroll 1
    for (int kt = 0; kt < 16; ++kt) {
        int m0 = m_base + kt * 64;
        __syncthreads();                               // prev P/V readers done
        #pragma unroll
        for (int i = 0; i < 4; ++i) {                  // stage K-tile [64][128]
            int idx = i * 256 + tid, row = idx >> 4, ch = idx & 15;
            *(short8*)(KP + row * 136 + ch * 8) =
                *(const short8*)(Kb + (m0 + row) * 128 + ch * 8);
        }
        #pragma unroll
        for (int i = 0; i < 8; ++i) {                  // stage V-tile [256][64]
            int idx = i * 256 + tid, row = idx >> 3, ch = idx & 7;
            *(short8*)(Vs + row * 72 + ch * 8) =
                *(const short8*)(Vb + row * 4096 + m0 + ch * 8);
        }
        __syncthreads();

        // S^T[m][n]: row = m-within-16 (quad*4+reg), col = n (l16)
        f32x4 S[2][4];
        #pragma unroll
        for (int r = 0; r < 2; ++r)
            #pragma unroll
            for (int j = 0; j < 4; ++j) S[r][j] = (f32x4){0.f,0.f,0.f,0.f};
        #pragma unroll
        for (int ksub = 0; ksub < 4; ++ksub) {
            #pragma unroll
            for (int kk = 0; kk < 4; ++kk) {
                short8 kf = *(const short8*)(KP + (ksub * 16 + l16) * 136 + kk * 32 + quad * 8);
                S[0][ksub] = MFMA_BF16(kf, qf[0][kk], S[0][ksub], 0, 0, 0);
                S[1][ksub] = MFMA_BF16(kf, qf[1][kk], S[1][ksub], 0, 0, 0);
            }
        }
        __syncthreads();                               // K reads done -> P overlay ok

        // online softmax per query n = n0 + r*16 + l16 (replicated over quads)
        #pragma unroll
        for (int r = 0; r < 2; ++r) {
            float mx = -1e30f;
            #pragma unroll
            for (int ksub = 0; ksub < 4; ++ksub)
                #pragma unroll
                for (int reg = 0; reg < 4; ++reg) mx = fmaxf(mx, S[r][ksub][reg]);
            mx = fmaxf(mx, __shfl_xor(mx, 16));
            mx = fmaxf(mx, __shfl_xor(mx, 32));
            float mnew  = fmaxf(m_run[r], mx);
            float alpha = __expf(m_run[r] - mnew);
            float rs = 0.f;
            #pragma unroll
            for (int ksub = 0; ksub < 4; ++ksub) {
                u16x4 pk;
                #pragma unroll
                for (int reg = 0; reg < 4; ++reg) {
                    float p = __expf(S[r][ksub][reg] - mnew);
                    rs += p;
                    pk[reg] = f2bf(p);
                }
                // P[n][m]: n = r*16+l16, m = ksub*16 + quad*4 + reg  -> b64
                *(u16x4*)(Pw + (r * 16 + l16) * 72 + ksub * 16 + quad * 4) = pk;
            }
            rs += __shfl_xor(rs, 16);
            rs += __shfl_xor(rs, 32);
            l_run[r] = l_run[r] * alpha + rs;
            m_run[r] = mnew;
            // transpose alpha to O-row indexing (O rows n' = quad*4+reg)
            float a0 = __shfl(alpha, quad * 4 + 0);
            float a1 = __shfl(alpha, quad * 4 + 1);
            float a2 = __shfl(alpha, quad * 4 + 2);
            float a3 = __shfl(alpha, quad * 4 + 3);
            #pragma unroll
            for (int t = 0; t < 16; ++t) {
                O[r][t][0] *= a0; O[r][t][1] *= a1;
                O[r][t][2] *= a2; O[r][t][3] *= a3;
            }
        }

        // PV: O[n,c] += P[n,m] V[m,c]  (Pw per-wave private: no barrier needed)
        #pragma unroll
        for (int s = 0; s < 2; ++s) {
            short8 a0 = *(const short8*)(Pw + (l16) * 72 + s * 32 + quad * 8);
            short8 a1 = *(const short8*)(Pw + (16 + l16) * 72 + s * 32 + quad * 8);
            #pragma unroll
            for (int t = 0; t < 16; ++t) {
                short8 bv = *(const short8*)(Vs + (t * 16 + l16) * 72 + s * 32 + quad * 8);
                O[0][t] = MFMA_BF16(a0, bv, O[0][t], 0, 0, 0);
                O[1][t] = MFMA_BF16(a1, bv, O[1][t], 0, 0, 0);
            }
        }
    }

    // epilogue: unnormalized O (bf16) + per-query m,l
    unsigned short* Op = Opart + ((size_t)(ks * 4 + b) << 20);
    #pragma unroll
    for (int r = 0; r < 2; ++r)
        #pragma unroll
        for (int t = 0; t < 16; ++t)
            #pragma unroll
            for (int reg = 0; reg < 4; ++reg) {
                int n = n0 + r * 16 + quad * 4 + reg;
                int c = t * 16 + l16;
                Op[n * 256 + c] = f2bf(O[r][t][reg]);
            }
    if (lane < 16) {
        #pragma unroll
        for (int r = 0; r < 2; ++r) {
            int n = n0 + r * 16 + lane;
            Mpart[(ks * 4 + b) * 4096 + n] = m_run[r];
            Lpart[(ks * 4 + b) * 4096 + n] = l_run[r];
        }
    }
}

// --- K4: merge 4 key-splits, normalize, gamma*O+x, transpose [n,c]->[c,n] --
__global__ __launch_bounds__(256) void merge_out(
        const unsigned short* __restrict__ Opart, const float* __restrict__ Mpart,
        const float* __restrict__ Lpart, const float* __restrict__ x,
        const float* __restrict__ gamma, float* __restrict__ out) {
    __shared__ float tile[64][65];
    __shared__ float wsm[4][64];                       // merge weights per n
    int b  = blockIdx.x >> 6;
    int n0 = (blockIdx.x & 63) << 6;
    int tid = threadIdx.x;
    float g = gamma[0];
    if (tid < 64) {
        int n = n0 + tid;
        float ms[4], M = -1e30f;
        #pragma unroll
        for (int s = 0; s < 4; ++s) {
            ms[s] = Mpart[(s * 4 + b) * 4096 + n];
            M = fmaxf(M, ms[s]);
        }
        float e[4], L = 0.f;
        #pragma unroll
        for (int s = 0; s < 4; ++s) {
            e[s] = __expf(ms[s] - M);
            L += e[s] * Lpart[(s * 4 + b) * 4096 + n];
        }
        float inv = g / L;
        #pragma unroll
        for (int s = 0; s < 4; ++s) wsm[s][tid] = e[s] * inv;
    }
    __syncthreads();
    int cl  = tid & 63, nl4 = tid >> 6;                // phase 1
    int nl  = tid & 63, cl4 = tid >> 6;                // phase 2
    for (int cc = 0; cc < 4; ++cc) {
        for (int i = 0; i < 16; ++i) {                 // phase 1: coalesced Opart reads
            int n = n0 + i * 4 + nl4;
            int c = (cc << 6) + cl;
            float On = 0.f;
            #pragma unroll
            for (int s = 0; s < 4; ++s)
                On += wsm[s][i * 4 + nl4] * bf2f(Opart[((size_t)(s * 4 + b) << 20) + n * 256 + c]);
            tile[cl][i * 4 + nl4] = On;
        }
        __syncthreads();
        for (int j = 0; j < 16; ++j) {                 // phase 2: coalesced out writes
            int c = (cc << 6) + j * 4 + cl4;
            int idx = (b << 20) + c * 4096 + n0 + nl;
            out[idx] = tile[j * 4 + cl4][nl] + x[idx];
        }
        __syncthreads();
    }
}

// ---------------------------------------------------------------------------
extern "C" void kernel_launch(void* const* d_in, const int* in_sizes, int n_in,
                              void* d_out, int out_size, void* d_ws, size_t ws_size,
                              hipStream_t stream) {
    const float* x     = (const float*)d_in[0];
    const float* Wq    = (const float*)d_in[1];
    const float* bq    = (const float*)d_in[2];
    const float* Wk    = (const float*)d_in[3];
    const float* bk    = (const float*)d_in[4];
    const float* Wv    = (const float*)d_in[5];
    const float* bv    = (const float*)d_in[6];
    const float* gamma = (const float*)d_in[7];
    float* out = (float*)d_out;

    if (ws_size < 51120128u) return;   // need ~49 MB scratch

    char* ws = (char*)d_ws;
    unsigned short* Wt    = (unsigned short*)(ws);             //    262,144 B
    float*          bias  = (float*)        (ws +   262144);   //      2,048 B
    unsigned short* Qrm   = (unsigned short*)(ws +   264192);  //  4,194,304 B
    unsigned short* Krm   = (unsigned short*)(ws +  4458496);  //  4,194,304 B
    unsigned short* Vbf   = (unsigned short*)(ws +  8652800);  //  8,388,608 B
    unsigned short* Opart = (unsigned short*)(ws + 17041408);  // 33,554,432 B
    float*          Mpart = (float*)        (ws + 50595840);   //    262,144 B
    float*          Lpart = (float*)        (ws + 50857984);   //    262,144 B

    prep_w   <<<512, 256, 0, stream>>>(Wq, bq, Wk, bk, Wv, bv, Wt, bias);
    proj     <<<512, 256, 0, stream>>>(x, Wt, bias, Qrm, Krm, Vbf);
    attn     <<<512, 256, 0, stream>>>(Qrm, Krm, Vbf, Opart, Mpart, Lpart);
    merge_out<<<256, 256, 0, stream>>>(Opart, Mpart, Lpart, x, gamma, out);
}